// Round 8
// baseline (112.827 us; speedup 1.0000x reference)
//
#include <hip/hip_runtime.h>
#include <hip/hip_bf16.h>

#define DEVI __device__ __forceinline__

constexpr int B_ = 32, CI = 128, CM = 256, H_ = 32, W_ = 32;
constexpr int S_ = 1024, NB = 100;
constexpr float LAMF = 0.7f, ILAMF = 0.3f, SCALEF = 3.0f;
// chunked channel-last activation layouts: [b][ch/8][pos][8ch]
constexpr size_t XSZ = (size_t)32 * 16 * 1156 * 8;   // per-ab xpad elems (34x34 pos)
constexpr size_t XBS = (size_t)16 * 1156 * 8;        // per-b stride
constexpr size_t CSZ = (size_t)32 * 32 * 324 * 8;    // per-ab cpad elems (18x18 pos)
constexpr size_t CBS = (size_t)32 * 324 * 8;

typedef short bf8 __attribute__((ext_vector_type(8)));
typedef float f4 __attribute__((ext_vector_type(4)));
typedef unsigned short u16;
typedef unsigned int u32;

struct alignas(8) us4 { u16 v[4]; };
struct alignas(16) us8 { u16 v[8]; };

// deconv tap order, parity-grouped: par0{0,2,6,8} par1{1,7} par2{3,5} par3{4}
__device__ __constant__ int TAPD9c[9] = {0, 2, 6, 8, 1, 7, 3, 5, 4};

DEVI u16 f2bf(float f) {
    unsigned u = __builtin_bit_cast(unsigned, f);
    u += 0x7FFFu + ((u >> 16) & 1u);
    return (u16)(u >> 16);
}
DEVI float bf2f(u16 h) {
    unsigned u = ((unsigned)h) << 16;
    return __builtin_bit_cast(float, u);
}

DEVI void gll16(const void* g, void* l) {
    __builtin_amdgcn_global_load_lds(
        (const __attribute__((address_space(1))) u32*)g,
        (__attribute__((address_space(3))) u32*)l, 16, 0, 0);
}

DEVI float waveSum(float v) {
#pragma unroll
    for (int off = 32; off > 0; off >>= 1) v += __shfl_down(v, off, 64);
    return v;
}
DEVI float blockSum256(float v, float* lds4) {
    v = waveSum(v);
    int wid = threadIdx.x >> 6, lane = threadIdx.x & 63;
    __syncthreads();
    if (lane == 0) lds4[wid] = v;
    __syncthreads();
    return lds4[0] + lds4[1] + lds4[2] + lds4[3];
}
DEVI float blockSum128(float v, float* lds2) {
    v = waveSum(v);
    int wid = threadIdx.x >> 6, lane = threadIdx.x & 63;
    __syncthreads();
    if (lane == 0) lds2[wid] = v;
    __syncthreads();
    return lds2[0] + lds2[1];
}
DEVI float blockMax128(float v, float* lds2) {
#pragma unroll
    for (int off = 32; off > 0; off >>= 1) v = fmaxf(v, __shfl_down(v, off, 64));
    int wid = threadIdx.x >> 6, lane = threadIdx.x & 63;
    __syncthreads();
    if (lane == 0) lds2[wid] = v;
    __syncthreads();
    return fmaxf(lds2[0], lds2[1]);
}

// ---- weight prep: staging-linear k-slot-major layouts ----
// A1p: [Mt2][kc36][s512][8e]  s -> (q=s>>7, m=s&127); oc=Mt*128+m, ch=(kc&3)*32+q*8+e, tap=kc>>2
// A2p/A3p: [kc72][s512][8e]   s -> (q,m); ch=(kc&7)*32+q*8+e, tap=kc>>3 (A3p via TAPD9c)
__global__ __launch_bounds__(256) void k_prep_w(const float* __restrict__ We,
                                                const float* __restrict__ Wf,
                                                const float* __restrict__ Wd,
                                                u16* __restrict__ A1p,
                                                u16* __restrict__ A2p,
                                                u16* __restrict__ A3p) {
    int i = blockIdx.x * 256 + threadIdx.x;  // 294912
    {
        int e = i & 7, s = (i >> 3) & 511, j = i >> 12;  // j 0..71
        int Mt = j / 36, kc = j - Mt * 36;
        int tap = kc >> 2, cq = kc & 3;
        int q = s >> 7, m = s & 127;
        int oc = Mt * 128 + m, ch = cq * 32 + q * 8 + e;
        A1p[i] = f2bf(We[((size_t)oc * CI + ch) * 9 + tap]);
    }
    {
        int e = i & 7, s = (i >> 3) & 511, kc = i >> 12;  // 0..71
        int tapi = kc >> 3, cq = kc & 7;
        int q = s >> 7, m = s & 127;
        int ch = cq * 32 + q * 8 + e;
        A2p[i] = f2bf(Wf[((size_t)m * CM + ch) * 9 + tapi]);
        A3p[i] = f2bf(Wd[((size_t)m * CM + ch) * 9 + TAPD9c[tapi]]);
    }
}

// ---- proxies ----
__global__ __launch_bounds__(128) void k_prox(const float* __restrict__ P,
                                              float* __restrict__ PnT,
                                              float* __restrict__ pn2) {
    __shared__ float lds2[2];
    int k = blockIdx.x, t = threadIdx.x;
    float v = P[k * CI + t];
    float ss = blockSum128(v * v, lds2);
    float sc = SCALEF / fmaxf(sqrtf(ss), 1e-12f);
    float pv = v * sc;
    PnT[t * NB + k] = pv;
    float s2 = blockSum128(pv * pv, lds2);
    if (t == 0) pn2[k] = s2;
}

// ---- zero the padding rings of xpad and cpad ----
__global__ __launch_bounds__(256) void k_ring(u16* __restrict__ xpad, u16* __restrict__ cpad) {
    int b = blockIdx.x, ab = blockIdx.y, t = threadIdx.x;
    u16* xp = xpad + (size_t)ab * XSZ + (size_t)b * XBS;
    u16* cp = cpad + (size_t)ab * CSZ + (size_t)b * CBS;
    us8 z = {};
    for (int i = t; i < 132 * 16; i += 256) {
        int cc = i / 132, rp = i - cc * 132;
        int pos;
        if (rp < 68) pos = (rp < 34) ? (32 * 34 + rp) : (33 * 34 + rp - 34);
        else { int r2 = rp - 68; pos = (r2 >> 1) * 34 + 32 + (r2 & 1); }
        *(us8*)(xp + ((size_t)cc * 1156 + pos) * 8) = z;
    }
    for (int i = t; i < 68 * 32; i += 256) {
        int cc = i / 68, rp = i - cc * 68;
        int pos;
        if (rp < 36) pos = (rp < 18) ? rp : (17 * 18 + rp - 18);
        else { int r2 = rp - 36; pos = (1 + (r2 >> 1)) * 18 + ((r2 & 1) ? 17 : 0); }
        *(us8*)(cp + ((size_t)cc * 324 + pos) * 8) = z;
    }
}

// ---- fused: x -> bf16 chunked xpad + invd (LDS-only) + meanx/meanfl ----
__global__ __launch_bounds__(256) void k_xpose(const float* __restrict__ xa,
                                               const float* __restrict__ xb,
                                               u16* __restrict__ xpad,
                                               float* __restrict__ meanbuf) {
    __shared__ float ldsx[128][64];   // 32KB
    __shared__ float sred[256];
    __shared__ float sinv[64];
    int b = blockIdx.x, yg = blockIdx.y, ab = blockIdx.z;
    int t = threadIdx.x;
    const float* x = (ab ? xb : xa) + (size_t)b * CI * S_ + yg * 64;
    int c4 = t >> 6, p = t & 63;
    for (int c0 = 0; c0 < 32; ++c0) {
        int c = c0 * 4 + c4;
        ldsx[c][p] = x[(size_t)c * S_ + p];
    }
    __syncthreads();
    int qc = t >> 6;
    int y = yg * 2 + (p >> 5), xcol = p & 31;
    u16* ox = xpad + (size_t)ab * XSZ + (size_t)b * XBS;
    float ss = 0.f;
#pragma unroll
    for (int c8 = 0; c8 < 4; ++c8) {
        int cb = qc * 32 + c8 * 8;
        int cc = cb >> 3;
        us8 pk;
#pragma unroll
        for (int j = 0; j < 8; ++j) {
            float v = ldsx[cb + j][p];
            ss = fmaf(v, v, ss);
            pk.v[j] = f2bf(v);
        }
        *(us8*)(ox + ((size_t)cc * 1156 + y * 34 + xcol) * 8) = pk;
    }
    sred[t] = ss;
    __syncthreads();
    if (t < 64) {
        float s = sred[t] + sred[t + 64] + sred[t + 128] + sred[t + 192];
        sinv[t] = 1.f / fmaxf(sqrtf(s), 1e-12f);
    }
    __syncthreads();
    int c = t >> 1, h = t & 1;
    float sx = 0.f, sf = 0.f;
    for (int i = 0; i < 32; ++i) {
        int p2 = h * 32 + ((i + c) & 31);
        float v = ldsx[c][p2];
        sx += v;
        sf = fmaf(v, sinv[p2], sf);
    }
    sx += __shfl_xor(sx, 1, 64);
    sf += __shfl_xor(sf, 1, 64);
    if (!(t & 1)) {
        atomicAdd(&meanbuf[(size_t)ab * 4096 + b * 128 + c], sx * (1.f / 1024.f));
        atomicAdd(&meanbuf[8192 + (size_t)ab * 4096 + b * 128 + c], sf * (1.f / 1024.f));
    }
}

// ---- conv1: LDS dbuf, tile M128 x N64, wave M64 x N32, 2 blocks/CU ----
// grid (4 Nt, 32 b, 4: Mt*2+ab)  [unchanged from R6 for clean A/B on k_cde]
__global__ __launch_bounds__(256, 2) void k_conv1g(const u16* __restrict__ XC,
                                                   const u16* __restrict__ A1p,
                                                   u16* __restrict__ CC) {
    __shared__ u16 sA[2][4096];   // [q4][m128][8] per buf (8KB)
    __shared__ u16 sB[2][2048];   // [q4][n64][8] per buf (4KB)
    int t = threadIdx.x, l = t & 63, l15 = l & 15, lq = l >> 4, w = t >> 6;
    int wm = w & 1, wn = w >> 1;
    int Nt = blockIdx.x, b = blockIdx.y;
    int ab = blockIdx.z & 1, Mt = blockIdx.z >> 1;
    const u16* xc = XC + (size_t)ab * XSZ + (size_t)b * XBS;
    const u16* Ag = A1p + (size_t)Mt * (36 * 4096);
    int bpos0 = (8 * Nt + 2 * (l >> 4)) * 34 + 2 * (l & 15);
    const int po1[9] = {0, 1, 2, 34, 35, 36, 68, 69, 70};

    auto stageA = [&](int buf, int kc) {
        const u16* ga = Ag + (size_t)kc * 4096 + t * 8;
        u16* da = &sA[buf][w * 512];
        gll16(ga, da);
        gll16(ga + 2048, da + 2048);
    };
    auto stageB = [&](int buf, int po, int cq) {
        int cc = cq * 4 + w;
        gll16(xc + ((size_t)cc * 1156 + bpos0 + po) * 8, &sB[buf][w * 512]);
    };

    f4 acc[4][2] = {};
    stageA(0, 0);
    stageB(0, 0, 0);
    int cur = 0;
#pragma unroll
    for (int ti = 0; ti < 9; ++ti) {
        const int po = po1[ti];
        const int poN = (ti < 8) ? po1[ti + 1] : 0;
#pragma unroll 1
        for (int q = 0; q < 4; ++q) {
            __syncthreads();
            int kc = ti * 4 + q;
            if (kc + 1 < 36) {
                stageA(cur ^ 1, kc + 1);
                stageB(cur ^ 1, (q + 1 < 4) ? po : poN, (q + 1 < 4) ? q + 1 : 0);
            }
            const u16* As = sA[cur];
            const u16* Bs = sB[cur];
            bf8 af[4], bv[2];
#pragma unroll
            for (int mf = 0; mf < 4; ++mf)
                af[mf] = *(const bf8*)(As + lq * 1024 + (wm * 64 + mf * 16 + l15) * 8);
#pragma unroll
            for (int nf = 0; nf < 2; ++nf)
                bv[nf] = *(const bf8*)(Bs + lq * 512 + (wn * 32 + nf * 16 + l15) * 8);
#pragma unroll
            for (int mf = 0; mf < 4; ++mf)
#pragma unroll
                for (int nf = 0; nf < 2; ++nf)
                    acc[mf][nf] = __builtin_amdgcn_mfma_f32_16x16x32_bf16(af[mf], bv[nf], acc[mf][nf], 0, 0, 0);
            cur ^= 1;
        }
    }
    u16* cb = CC + (size_t)ab * CSZ + (size_t)b * CBS;
#pragma unroll
    for (int mf = 0; mf < 4; ++mf) {
        int mc = Mt * 128 + wm * 64 + mf * 16 + lq * 4;
#pragma unroll
        for (int nf = 0; nf < 2; ++nf) {
            int nl = wn * 32 + nf * 16 + l15;
            int oh = Nt * 4 + (nl >> 4), ow = nl & 15;
            int posO = (1 + oh) * 18 + 1 + ow;
            us4 pk;
#pragma unroll
            for (int r = 0; r < 4; ++r) pk.v[r] = f2bf(fmaxf(acc[mf][nf][r], 0.f));
            *(us4*)(cb + ((size_t)(mc >> 3) * 324 + posO) * 8 + (mc & 7)) = pk;
        }
    }
}

// ---- conv2 (type0) + deconv parity-set blocks (type1: par{0,3}, type2: par{1,2}) ----
// tile M128 x N128, 16 MFMA / 16KB staged per step. grid (2 Nt, 32 b, 6: type*2+ab)
__global__ __launch_bounds__(256, 2) void k_cde4(const u16* __restrict__ CC,
                                                 const u16* __restrict__ A2p,
                                                 const u16* __restrict__ A3p,
                                                 const u16* __restrict__ XC,
                                                 float* __restrict__ feats,
                                                 float* __restrict__ pr) {
    __shared__ u16 sA[2][4096];   // [q4][m128][8e] 8KB per buf
    __shared__ u16 sB[2][4096];   // [q4][n128][8e] 8KB per buf
    __shared__ float lds4[4];
    int t = threadIdx.x, l = t & 63, l15 = l & 15, lq = l >> 4, w = t >> 6;
    int wm = w & 1, wn = w >> 1;
    int Nt = blockIdx.x, b = blockIdx.y;
    int ab = blockIdx.z & 1, type = blockIdx.z >> 1;
    const u16* cbb = CC + (size_t)ab * CSZ + (size_t)b * CBS;
    const u16* xq = XC + (size_t)ab * XSZ + (size_t)b * XBS;
    const u16* Ag = type ? A3p : A2p;
    // B staging: slot = j*256 + t -> q = j*2 + (t>>7), n = t&127
    int bposB = (8 * Nt + ((t & 127) >> 4)) * 18 + (t & 15);
    int qhi = t >> 7;

    f4 acc[4][4] = {};
    float ss = 0.f;

    auto stageA = [&](int buf, int kcA) {
        const u16* ga = Ag + (size_t)kcA * 4096 + t * 8;
        u16* da = &sA[buf][w * 512];
        gll16(ga, da);
        gll16(ga + 2048, da + 2048);
    };
    auto stageB = [&](int buf, int po, int cq) {
        gll16(cbb + ((size_t)((cq * 4 + qhi) * 324) + bposB + po) * 8, &sB[buf][w * 512]);
        gll16(cbb + ((size_t)((cq * 4 + 2 + qhi) * 324) + bposB + po) * 8, &sB[buf][2048 + w * 512]);
    };
    auto kstep = [&](int cur, bool hn, int kAn, int poN, int cqN) {
        __syncthreads();
        if (hn) { stageA(cur ^ 1, kAn); stageB(cur ^ 1, poN, cqN); }
        const u16* As = sA[cur];
        const u16* Bs = sB[cur];
        bf8 af[4], bv[4];
#pragma unroll
        for (int mf = 0; mf < 4; ++mf)
            af[mf] = *(const bf8*)(As + (lq * 128 + wm * 64 + mf * 16 + l15) * 8);
#pragma unroll
        for (int nf = 0; nf < 4; ++nf)
            bv[nf] = *(const bf8*)(Bs + (lq * 128 + wn * 64 + nf * 16 + l15) * 8);
#pragma unroll
        for (int mf = 0; mf < 4; ++mf)
#pragma unroll
            for (int nf = 0; nf < 4; ++nf)
                acc[mf][nf] = __builtin_amdgcn_mfma_f32_16x16x32_bf16(af[mf], bv[nf], acc[mf][nf], 0, 0, 0);
    };
    auto flush = [&](int py, int px) {
#pragma unroll
        for (int mf = 0; mf < 4; ++mf) {
            int mc = wm * 64 + mf * 16 + lq * 4;
            const u16* xrow = xq + (size_t)(mc >> 3) * 1156 * 8 + (mc & 7);
#pragma unroll
            for (int nf = 0; nf < 4; ++nf) {
                int n = wn * 64 + nf * 16 + l15;
                int oh = 8 * Nt + (n >> 4), ow = n & 15;
                int Y = 2 * oh + py, X = 2 * ow + px;
                us4 xv = *(const us4*)(xrow + (size_t)(Y * 34 + X) * 8);
#pragma unroll
                for (int r = 0; r < 4; ++r) {
                    float d = acc[mf][nf][r] - bf2f(xv.v[r]);
                    ss = fmaf(d, d, ss);
                }
                f4 z = {0.f, 0.f, 0.f, 0.f};
                acc[mf][nf] = z;
            }
        }
    };

    int cur = 0;
    if (type == 0) {
        // conv2: taps 0..8 linear, K = 72 kc
        const int POT[9] = {0, 1, 2, 18, 19, 20, 36, 37, 38};
        stageA(0, 0);
        stageB(0, 0, 0);
#pragma unroll
        for (int ti = 0; ti < 9; ++ti) {
            const int po = POT[ti];
            const int poN = (ti < 8) ? POT[ti + 1] : 0;
#pragma unroll 1
            for (int q = 0; q < 8; ++q) {
                int kc = ti * 8 + q;
                kstep(cur, kc < 71, kc + 1, (q < 7) ? po : poN, (q < 7) ? q + 1 : 0);
                cur ^= 1;
            }
        }
        float* fo = feats + ((size_t)ab * B_ + b) * CI;
#pragma unroll
        for (int mf = 0; mf < 4; ++mf)
#pragma unroll
            for (int r = 0; r < 4; ++r) {
                float v = 0.f;
#pragma unroll
                for (int nf = 0; nf < 4; ++nf) v += fmaxf(acc[mf][nf][r], 0.f);
                v += __shfl_xor(v, 1, 64);
                v += __shfl_xor(v, 2, 64);
                v += __shfl_xor(v, 4, 64);
                v += __shfl_xor(v, 8, 64);
                if (l15 == 0)
                    atomicAdd(fo + wm * 64 + mf * 16 + lq * 4 + r, v * (1.f / 256.f));
            }
    } else if (type == 1) {
        // deconv parities {0,3}: taps {0,2,6,8} then {4}; A3p chunks {0,1,2,3,8}
        const int TIX[5] = {0, 1, 2, 3, 8};
        const int POD[5] = {0, 1, 18, 19, 19};
        stageA(0, 0);
        stageB(0, 0, 0);
#pragma unroll
        for (int ti = 0; ti < 5; ++ti) {
            const int po = POD[ti];
            const int poN = (ti < 4) ? POD[ti + 1] : 0;
            const int kA0 = TIX[ti] * 8;
            const int kA0N = (ti < 4) ? TIX[ti + 1] * 8 : 0;
#pragma unroll 1
            for (int q = 0; q < 8; ++q) {
                int kc = ti * 8 + q;
                kstep(cur, kc < 39, (q < 7) ? kA0 + q + 1 : kA0N, (q < 7) ? po : poN,
                      (q < 7) ? q + 1 : 0);
                cur ^= 1;
            }
            if (ti == 3) flush(0, 0);
            else if (ti == 4) flush(1, 1);
        }
        ss = blockSum256(ss, lds4);
        if (t == 0) atomicAdd(pr + ab, ss);
    } else {
        // deconv parities {1,2}: taps {1,7} then {3,5}; A3p chunks {4,5,6,7}
        const int TIX[4] = {4, 5, 6, 7};
        const int POD[4] = {1, 19, 18, 19};
        stageA(0, 32);
        stageB(0, 1, 0);
#pragma unroll
        for (int ti = 0; ti < 4; ++ti) {
            const int po = POD[ti];
            const int poN = (ti < 3) ? POD[ti + 1] : 0;
            const int kA0 = TIX[ti] * 8;
            const int kA0N = (ti < 3) ? TIX[ti + 1] * 8 : 0;
#pragma unroll 1
            for (int q = 0; q < 8; ++q) {
                int kc = ti * 8 + q;
                kstep(cur, kc < 31, (q < 7) ? kA0 + q + 1 : kA0N, (q < 7) ? po : poN,
                      (q < 7) ? q + 1 : 0);
                cur ^= 1;
            }
            if (ti == 1) flush(0, 1);
            else if (ti == 3) flush(1, 0);
        }
        ss = blockSum256(ss, lds4);
        if (t == 0) atomicAdd(pr + ab, ss);
    }
}

// ---- metric (mix fused: sets 2/3 from meanbuf; Sinkhorn dead code) ----
__global__ __launch_bounds__(128) void k_metric(const float* __restrict__ feats,
                                                const float* __restrict__ meanbuf,
                                                const float* __restrict__ PnT,
                                                const float* __restrict__ pn2,
                                                const int* __restrict__ la,
                                                const int* __restrict__ lb,
                                                float* __restrict__ mo) {
    __shared__ float lds2[2];
    __shared__ float xs[128];
    int blk = blockIdx.x;
    int t = threadIdx.x;
    int b = blk & 31;
    float xv;
    if (blk < 64) xv = feats[(size_t)blk * CI + t];
    else if (blk < 96) xv = LAMF * meanbuf[b * 128 + t] + ILAMF * meanbuf[12288 + b * 128 + t];
    else xv = LAMF * meanbuf[4096 + b * 128 + t] + ILAMF * meanbuf[8192 + b * 128 + t];
    float ssq = blockSum128(xv * xv, lds2);
    float sc = SCALEF / fmaxf(sqrtf(ssq), 1e-12f);
    float xn = xv * sc;
    xs[t] = xn;
    float xn2 = blockSum128(xn * xn, lds2);
    bool active = (t < NB);
    float Dk = 1e30f;
    if (active) {
        float dot = 0.f;
#pragma unroll 8
        for (int e = 0; e < CI; ++e) dot = fmaf(xs[e], PnT[e * NB + t], dot);
        Dk = xn2 + pn2[t] - 2.f * dot;
    }
    float z = active ? -Dk : -1e30f;
    float m = blockMax128(z, lds2);
    float e = active ? expf(z - m) : 0.f;
    float se = blockSum128(e, lds2);
    float lse = m + logf(se);
    if (t == 0) mo[blk * 3 + 0] = lse;
    int A = la[b], Bb = lb[b];
    if (t == A) mo[blk * 3 + 1] = Dk;
    if (t == Bb) mo[blk * 3 + 2] = Dk;
}

__global__ __launch_bounds__(128) void k_final(const float* __restrict__ pr,
                                               const float* __restrict__ mo,
                                               float* __restrict__ out) {
    __shared__ float mla[4], mlb[4];
    int t = threadIdx.x;
    const float* m = mo + t * 3;
    float ula = m[0] + m[1];
    float ulb = m[0] + m[2];
#pragma unroll
    for (int off = 16; off > 0; off >>= 1) {
        ula += __shfl_down(ula, off, 32);
        ulb += __shfl_down(ulb, off, 32);
    }
    if ((t & 31) == 0) { mla[t >> 5] = ula * (1.f / 32.f); mlb[t >> 5] = ulb * (1.f / 32.f); }
    __syncthreads();
    if (t == 0) {
        float lxa = pr[0] * (1.f / 4194304.f);
        float lxb = pr[1] * (1.f / 4194304.f);
        float lca = mla[0];
        float lcb = mlb[1];
        float lcma = LAMF * mla[2] + ILAMF * mlb[2];
        float lcmb = LAMF * mlb[3] + ILAMF * mla[3];
        out[0] = lxa + lxb + lca + lcb + lcma + lcmb;
        out[1] = lxa; out[2] = lxb; out[3] = lca; out[4] = lcb; out[5] = lcma; out[6] = lcmb;
    }
}

extern "C" void kernel_launch(void* const* d_in, const int* in_sizes, int n_in,
                              void* d_out, int out_size, void* d_ws, size_t ws_size,
                              hipStream_t stream) {
    const float* xa = (const float*)d_in[0];
    const float* xb = (const float*)d_in[1];
    const int* la = (const int*)d_in[2];
    const int* lb = (const int*)d_in[3];
    const float* P = (const float*)d_in[4];
    const float* We = (const float*)d_in[5];
    const float* Wf = (const float*)d_in[6];
    const float* Wd = (const float*)d_in[7];

    char* w = (char*)d_ws;
    const size_t XPAD_B = XSZ * 2 * sizeof(u16);
    const size_t CPAD_B = CSZ * 2 * sizeof(u16);
    const size_t AW_B = (size_t)294912 * 2;
    u16* xpad = (u16*)w;                 w += XPAD_B;
    u16* cpad = (u16*)w;                 w += CPAD_B;
    u16* A1p = (u16*)w;                  w += AW_B;
    u16* A2p = (u16*)w;                  w += AW_B;
    u16* A3p = (u16*)w;                  w += AW_B;
    float* PnT = (float*)w;              w += 12800 * 4;
    float* pn2 = (float*)w;              w += 128 * 4;
    float* feats = (float*)w;            w += 8192 * 4;    // [2 ab][32][128]
    float* meanbuf = (float*)w;          w += 16384 * 4;   // [2 kind][2 ab][32][128]
    float* pr = (float*)w;               w += 16 * 4;
    float* mo = (float*)w;               w += 384 * 4;
    float* out = (float*)d_out;

    hipMemsetAsync(feats, 0, (8192 + 16384 + 16) * sizeof(float), stream);

    k_prep_w<<<1152, 256, 0, stream>>>(We, Wf, Wd, A1p, A2p, A3p);
    k_prox<<<NB, 128, 0, stream>>>(P, PnT, pn2);
    k_ring<<<dim3(32, 2), 256, 0, stream>>>(xpad, cpad);
    k_xpose<<<dim3(32, 16, 2), 256, 0, stream>>>(xa, xb, xpad, meanbuf);
    k_conv1g<<<dim3(4, 32, 4), 256, 0, stream>>>(xpad, A1p, cpad);
    k_cde4<<<dim3(2, 32, 6), 256, 0, stream>>>(cpad, A2p, A3p, xpad, feats, pr);
    k_metric<<<128, 128, 0, stream>>>(feats, meanbuf, PnT, pn2, la, lb, mo);
    k_final<<<1, 128, 0, stream>>>(pr, mo, out);
}

// Round 9
// 109.531 us; speedup vs baseline: 1.0301x; 1.0301x over previous
//
#include <hip/hip_runtime.h>
#include <hip/hip_bf16.h>

#define DEVI __device__ __forceinline__

constexpr int B_ = 32, CI = 128, CM = 256, H_ = 32, W_ = 32;
constexpr int S_ = 1024, NB = 100;
constexpr float LAMF = 0.7f, ILAMF = 0.3f, SCALEF = 3.0f;
// chunked channel-last activation layouts: [b][ch/8][pos][8ch]
constexpr size_t XSZ = (size_t)32 * 16 * 1156 * 8;   // per-ab xpad elems (34x34 pos)
constexpr size_t XBS = (size_t)16 * 1156 * 8;        // per-b stride
constexpr size_t CSZ = (size_t)32 * 32 * 324 * 8;    // per-ab cpad elems (18x18 pos)
constexpr size_t CBS = (size_t)32 * 324 * 8;

typedef short bf8 __attribute__((ext_vector_type(8)));
typedef float f4 __attribute__((ext_vector_type(4)));
typedef unsigned short u16;
typedef unsigned int u32;

struct alignas(8) us4 { u16 v[4]; };
struct alignas(16) us8 { u16 v[8]; };

// deconv tap order, parity-grouped: par0{0,2,6,8} par1{1,7} par2{3,5} par3{4}
__device__ __constant__ int TAPD9c[9] = {0, 2, 6, 8, 1, 7, 3, 5, 4};

DEVI u16 f2bf(float f) {
    unsigned u = __builtin_bit_cast(unsigned, f);
    u += 0x7FFFu + ((u >> 16) & 1u);
    return (u16)(u >> 16);
}
DEVI float bf2f(u16 h) {
    unsigned u = ((unsigned)h) << 16;
    return __builtin_bit_cast(float, u);
}

DEVI void gll16(const void* g, void* l) {
    __builtin_amdgcn_global_load_lds(
        (const __attribute__((address_space(1))) u32*)g,
        (__attribute__((address_space(3))) u32*)l, 16, 0, 0);
}

DEVI float waveSum(float v) {
#pragma unroll
    for (int off = 32; off > 0; off >>= 1) v += __shfl_down(v, off, 64);
    return v;
}
DEVI float blockSum256(float v, float* lds4) {
    v = waveSum(v);
    int wid = threadIdx.x >> 6, lane = threadIdx.x & 63;
    __syncthreads();
    if (lane == 0) lds4[wid] = v;
    __syncthreads();
    return lds4[0] + lds4[1] + lds4[2] + lds4[3];
}
DEVI float blockSum128(float v, float* lds2) {
    v = waveSum(v);
    int wid = threadIdx.x >> 6, lane = threadIdx.x & 63;
    __syncthreads();
    if (lane == 0) lds2[wid] = v;
    __syncthreads();
    return lds2[0] + lds2[1];
}
DEVI float blockMax128(float v, float* lds2) {
#pragma unroll
    for (int off = 32; off > 0; off >>= 1) v = fmaxf(v, __shfl_down(v, off, 64));
    int wid = threadIdx.x >> 6, lane = threadIdx.x & 63;
    __syncthreads();
    if (lane == 0) lds2[wid] = v;
    __syncthreads();
    return fmaxf(lds2[0], lds2[1]);
}

// ---- weight prep: staging-linear k-slot-major layouts ----
// A1p: [Mt2][kc36][s512][8e]  s -> (q=s>>7, m=s&127); oc=Mt*128+m, ch=(kc&3)*32+q*8+e, tap=kc>>2
// A2p/A3p: [kc72][s512][8e]   s -> (q,m); ch=(kc&7)*32+q*8+e, tap=kc>>3 (A3p via TAPD9c)
__global__ __launch_bounds__(256) void k_prep_w(const float* __restrict__ We,
                                                const float* __restrict__ Wf,
                                                const float* __restrict__ Wd,
                                                u16* __restrict__ A1p,
                                                u16* __restrict__ A2p,
                                                u16* __restrict__ A3p) {
    int i = blockIdx.x * 256 + threadIdx.x;  // 294912
    {
        int e = i & 7, s = (i >> 3) & 511, j = i >> 12;  // j 0..71
        int Mt = j / 36, kc = j - Mt * 36;
        int tap = kc >> 2, cq = kc & 3;
        int q = s >> 7, m = s & 127;
        int oc = Mt * 128 + m, ch = cq * 32 + q * 8 + e;
        A1p[i] = f2bf(We[((size_t)oc * CI + ch) * 9 + tap]);
    }
    {
        int e = i & 7, s = (i >> 3) & 511, kc = i >> 12;  // 0..71
        int tapi = kc >> 3, cq = kc & 7;
        int q = s >> 7, m = s & 127;
        int ch = cq * 32 + q * 8 + e;
        A2p[i] = f2bf(Wf[((size_t)m * CM + ch) * 9 + tapi]);
        A3p[i] = f2bf(Wd[((size_t)m * CM + ch) * 9 + TAPD9c[tapi]]);
    }
}

// ---- proxies ----
__global__ __launch_bounds__(128) void k_prox(const float* __restrict__ P,
                                              float* __restrict__ PnT,
                                              float* __restrict__ pn2) {
    __shared__ float lds2[2];
    int k = blockIdx.x, t = threadIdx.x;
    float v = P[k * CI + t];
    float ss = blockSum128(v * v, lds2);
    float sc = SCALEF / fmaxf(sqrtf(ss), 1e-12f);
    float pv = v * sc;
    PnT[t * NB + k] = pv;
    float s2 = blockSum128(pv * pv, lds2);
    if (t == 0) pn2[k] = s2;
}

// ---- zero the padding rings of xpad and cpad ----
__global__ __launch_bounds__(256) void k_ring(u16* __restrict__ xpad, u16* __restrict__ cpad) {
    int b = blockIdx.x, ab = blockIdx.y, t = threadIdx.x;
    u16* xp = xpad + (size_t)ab * XSZ + (size_t)b * XBS;
    u16* cp = cpad + (size_t)ab * CSZ + (size_t)b * CBS;
    us8 z = {};
    for (int i = t; i < 132 * 16; i += 256) {
        int cc = i / 132, rp = i - cc * 132;
        int pos;
        if (rp < 68) pos = (rp < 34) ? (32 * 34 + rp) : (33 * 34 + rp - 34);
        else { int r2 = rp - 68; pos = (r2 >> 1) * 34 + 32 + (r2 & 1); }
        *(us8*)(xp + ((size_t)cc * 1156 + pos) * 8) = z;
    }
    for (int i = t; i < 68 * 32; i += 256) {
        int cc = i / 68, rp = i - cc * 68;
        int pos;
        if (rp < 36) pos = (rp < 18) ? rp : (17 * 18 + rp - 18);
        else { int r2 = rp - 36; pos = (1 + (r2 >> 1)) * 18 + ((r2 & 1) ? 17 : 0); }
        *(us8*)(cp + ((size_t)cc * 324 + pos) * 8) = z;
    }
}

// ---- fused: x -> bf16 chunked xpad + invd (LDS-only) + meanx/meanfl ----
__global__ __launch_bounds__(256) void k_xpose(const float* __restrict__ xa,
                                               const float* __restrict__ xb,
                                               u16* __restrict__ xpad,
                                               float* __restrict__ meanbuf) {
    __shared__ float ldsx[128][64];   // 32KB
    __shared__ float sred[256];
    __shared__ float sinv[64];
    int b = blockIdx.x, yg = blockIdx.y, ab = blockIdx.z;
    int t = threadIdx.x;
    const float* x = (ab ? xb : xa) + (size_t)b * CI * S_ + yg * 64;
    int c4 = t >> 6, p = t & 63;
    for (int c0 = 0; c0 < 32; ++c0) {
        int c = c0 * 4 + c4;
        ldsx[c][p] = x[(size_t)c * S_ + p];
    }
    __syncthreads();
    int qc = t >> 6;
    int y = yg * 2 + (p >> 5), xcol = p & 31;
    u16* ox = xpad + (size_t)ab * XSZ + (size_t)b * XBS;
    float ss = 0.f;
#pragma unroll
    for (int c8 = 0; c8 < 4; ++c8) {
        int cb = qc * 32 + c8 * 8;
        int cc = cb >> 3;
        us8 pk;
#pragma unroll
        for (int j = 0; j < 8; ++j) {
            float v = ldsx[cb + j][p];
            ss = fmaf(v, v, ss);
            pk.v[j] = f2bf(v);
        }
        *(us8*)(ox + ((size_t)cc * 1156 + y * 34 + xcol) * 8) = pk;
    }
    sred[t] = ss;
    __syncthreads();
    if (t < 64) {
        float s = sred[t] + sred[t + 64] + sred[t + 128] + sred[t + 192];
        sinv[t] = 1.f / fmaxf(sqrtf(s), 1e-12f);
    }
    __syncthreads();
    int c = t >> 1, h = t & 1;
    float sx = 0.f, sf = 0.f;
    for (int i = 0; i < 32; ++i) {
        int p2 = h * 32 + ((i + c) & 31);
        float v = ldsx[c][p2];
        sx += v;
        sf = fmaf(v, sinv[p2], sf);
    }
    sx += __shfl_xor(sx, 1, 64);
    sf += __shfl_xor(sf, 1, 64);
    if (!(t & 1)) {
        atomicAdd(&meanbuf[(size_t)ab * 4096 + b * 128 + c], sx * (1.f / 1024.f));
        atomicAdd(&meanbuf[8192 + (size_t)ab * 4096 + b * 128 + c], sf * (1.f / 1024.f));
    }
}

// ---- conv1: K-64 steps (18 total), tile M128 x N64, LDS dbuf 48KB ----
// grid (4 Nt, 32 b, 4: Mt*2+ab)
__global__ __launch_bounds__(256, 2) void k_conv1g(const u16* __restrict__ XC,
                                                   const u16* __restrict__ A1p,
                                                   u16* __restrict__ CC) {
    __shared__ u16 sA[2][8192];   // [ks8][m128][8] per buf (16KB)
    __shared__ u16 sB[2][4096];   // [ks8][n64][8] per buf (8KB)
    int t = threadIdx.x, l = t & 63, l15 = l & 15, lq = l >> 4, w = t >> 6;
    int wm = w & 1, wn = w >> 1;
    int Nt = blockIdx.x, b = blockIdx.y;
    int ab = blockIdx.z & 1, Mt = blockIdx.z >> 1;
    const u16* xc = XC + (size_t)ab * XSZ + (size_t)b * XBS;
    const u16* Ag = A1p + (size_t)Mt * (36 * 4096);
    int bpos0 = (8 * Nt + 2 * (l >> 4)) * 34 + 2 * (l & 15);
    const int po1[9] = {0, 1, 2, 34, 35, 36, 68, 69, 70};

    auto stageA = [&](int buf, int kcA) {   // 2 kc chunks = 16KB
        const u16* ga = Ag + (size_t)kcA * 4096 + t * 8;
        u16* da = &sA[buf][w * 512];
#pragma unroll
        for (int i = 0; i < 4; ++i) gll16(ga + i * 2048, da + i * 2048);
    };
    auto stageB = [&](int buf, int po, int s) {  // 8 k-slots x 64 n = 8KB
#pragma unroll
        for (int i = 0; i < 2; ++i) {
            int ks = i * 4 + w;
            gll16(xc + ((size_t)(s * 8 + ks) * 1156 + bpos0 + po) * 8,
                  &sB[buf][(size_t)ks * 512]);
        }
    };

    f4 acc[4][2] = {};
    stageA(0, 0);
    stageB(0, 0, 0);
    int cur = 0;
#pragma unroll
    for (int ti = 0; ti < 9; ++ti) {
        const int po = po1[ti];
        const int poN = (ti < 8) ? po1[ti + 1] : 0;
#pragma unroll 1
        for (int s = 0; s < 2; ++s) {
            __syncthreads();
            bool last = (ti == 8) && (s == 1);
            if (!last) {
                int tin = (s < 1) ? ti : ti + 1;
                int sn = (s < 1) ? 1 : 0;
                stageA(cur ^ 1, tin * 4 + sn * 2);
                stageB(cur ^ 1, (s < 1) ? po : poN, sn);
            }
            const u16* As = sA[cur];
            const u16* Bs = sB[cur];
#pragma unroll
            for (int kc2 = 0; kc2 < 2; ++kc2) {
                bf8 af[4], bv[2];
#pragma unroll
                for (int mf = 0; mf < 4; ++mf)
                    af[mf] = *(const bf8*)(As + ((kc2 * 4 + lq) * 128 + wm * 64 + mf * 16 + l15) * 8);
#pragma unroll
                for (int nf = 0; nf < 2; ++nf)
                    bv[nf] = *(const bf8*)(Bs + ((kc2 * 4 + lq) * 64 + wn * 32 + nf * 16 + l15) * 8);
#pragma unroll
                for (int mf = 0; mf < 4; ++mf)
#pragma unroll
                    for (int nf = 0; nf < 2; ++nf)
                        acc[mf][nf] = __builtin_amdgcn_mfma_f32_16x16x32_bf16(af[mf], bv[nf], acc[mf][nf], 0, 0, 0);
            }
            cur ^= 1;
        }
    }
    u16* cb = CC + (size_t)ab * CSZ + (size_t)b * CBS;
#pragma unroll
    for (int mf = 0; mf < 4; ++mf) {
        int mc = Mt * 128 + wm * 64 + mf * 16 + lq * 4;
#pragma unroll
        for (int nf = 0; nf < 2; ++nf) {
            int nl = wn * 32 + nf * 16 + l15;
            int oh = Nt * 4 + (nl >> 4), ow = nl & 15;
            int posO = (1 + oh) * 18 + 1 + ow;
            us4 pk;
#pragma unroll
            for (int r = 0; r < 4; ++r) pk.v[r] = f2bf(fmaxf(acc[mf][nf][r], 0.f));
            *(us4*)(cb + ((size_t)(mc >> 3) * 324 + posO) * 8 + (mc & 7)) = pk;
        }
    }
}

// ---- conv2 (type0) + deconv parity-sets (type1: par{0,3}, type2: par{1,2}) ----
// K-64 steps: type0 36, type1 20, type2 16. tile M128 x N128, LDS dbuf 64KB.
// grid (2 Nt, 32 b, 6: type*2+ab)
__global__ __launch_bounds__(256, 2) void k_cde5(const u16* __restrict__ CC,
                                                 const u16* __restrict__ A2p,
                                                 const u16* __restrict__ A3p,
                                                 const u16* __restrict__ XC,
                                                 float* __restrict__ feats,
                                                 float* __restrict__ pr) {
    __shared__ u16 sA[2][8192];   // [ks8][m128][8e] 16KB per buf
    __shared__ u16 sB[2][8192];   // [ks8][n128][8e] 16KB per buf
    __shared__ float lds4[4];
    int t = threadIdx.x, l = t & 63, l15 = l & 15, lq = l >> 4, w = t >> 6;
    int wm = w & 1, wn = w >> 1;
    int Nt = blockIdx.x, b = blockIdx.y;
    int ab = blockIdx.z & 1, type = blockIdx.z >> 1;
    const u16* cbb = CC + (size_t)ab * CSZ + (size_t)b * CBS;
    const u16* xq = XC + (size_t)ab * XSZ + (size_t)b * XBS;
    const u16* Ag = type ? A3p : A2p;
    int nloc = t & 127;
    int bposB = (8 * Nt + (nloc >> 4)) * 18 + (nloc & 15);
    int qh = w >> 1, nh = w & 1;

    f4 acc[4][4] = {};
    float ss = 0.f;

    auto stageA = [&](int buf, int kcA) {   // 2 kc chunks = 16KB
        const u16* ga = Ag + (size_t)kcA * 4096 + t * 8;
        u16* da = &sA[buf][w * 512];
#pragma unroll
        for (int i = 0; i < 4; ++i) gll16(ga + i * 2048, da + i * 2048);
    };
    auto stageB = [&](int buf, int po, int s) {  // 8 ks x 128 n = 16KB
#pragma unroll
        for (int i = 0; i < 4; ++i) {
            int ks = i * 2 + qh;
            gll16(cbb + ((size_t)(s * 8 + ks) * 324 + bposB + po) * 8,
                  &sB[buf][(size_t)ks * 1024 + nh * 512]);
        }
    };
    auto kstep = [&](int cur, bool hn, int kAn, int poN, int sN) {
        __syncthreads();
        if (hn) { stageA(cur ^ 1, kAn); stageB(cur ^ 1, poN, sN); }
        const u16* As = sA[cur];
        const u16* Bs = sB[cur];
#pragma unroll
        for (int kc2 = 0; kc2 < 2; ++kc2) {
            bf8 af[4], bv[4];
#pragma unroll
            for (int mf = 0; mf < 4; ++mf)
                af[mf] = *(const bf8*)(As + ((kc2 * 4 + lq) * 128 + wm * 64 + mf * 16 + l15) * 8);
#pragma unroll
            for (int nf = 0; nf < 4; ++nf)
                bv[nf] = *(const bf8*)(Bs + ((kc2 * 4 + lq) * 128 + wn * 64 + nf * 16 + l15) * 8);
#pragma unroll
            for (int mf = 0; mf < 4; ++mf)
#pragma unroll
                for (int nf = 0; nf < 4; ++nf)
                    acc[mf][nf] = __builtin_amdgcn_mfma_f32_16x16x32_bf16(af[mf], bv[nf], acc[mf][nf], 0, 0, 0);
        }
    };
    auto flush = [&](int py, int px) {
#pragma unroll
        for (int mf = 0; mf < 4; ++mf) {
            int mc = wm * 64 + mf * 16 + lq * 4;
            const u16* xrow = xq + (size_t)(mc >> 3) * 1156 * 8 + (mc & 7);
#pragma unroll
            for (int nf = 0; nf < 4; ++nf) {
                int n = wn * 64 + nf * 16 + l15;
                int oh = 8 * Nt + (n >> 4), ow = n & 15;
                int Y = 2 * oh + py, X = 2 * ow + px;
                us4 xv = *(const us4*)(xrow + (size_t)(Y * 34 + X) * 8);
#pragma unroll
                for (int r = 0; r < 4; ++r) {
                    float d = acc[mf][nf][r] - bf2f(xv.v[r]);
                    ss = fmaf(d, d, ss);
                }
                f4 z = {0.f, 0.f, 0.f, 0.f};
                acc[mf][nf] = z;
            }
        }
    };

    int cur = 0;
    if (type == 0) {
        // conv2: taps 0..8 linear, 36 K-64 steps
        const int POT[9] = {0, 1, 2, 18, 19, 20, 36, 37, 38};
        stageA(0, 0);
        stageB(0, 0, 0);
#pragma unroll
        for (int ti = 0; ti < 9; ++ti) {
            const int po = POT[ti];
            const int poN = (ti < 8) ? POT[ti + 1] : 0;
#pragma unroll 1
            for (int s = 0; s < 4; ++s) {
                bool last = (ti == 8) && (s == 3);
                int tin = (s < 3) ? ti : ti + 1;
                int sn = (s < 3) ? s + 1 : 0;
                kstep(cur, !last, tin * 8 + sn * 2, (s < 3) ? po : poN, sn);
                cur ^= 1;
            }
        }
        float* fo = feats + ((size_t)ab * B_ + b) * CI;
#pragma unroll
        for (int mf = 0; mf < 4; ++mf)
#pragma unroll
            for (int r = 0; r < 4; ++r) {
                float v = 0.f;
#pragma unroll
                for (int nf = 0; nf < 4; ++nf) v += fmaxf(acc[mf][nf][r], 0.f);
                v += __shfl_xor(v, 1, 64);
                v += __shfl_xor(v, 2, 64);
                v += __shfl_xor(v, 4, 64);
                v += __shfl_xor(v, 8, 64);
                if (l15 == 0)
                    atomicAdd(fo + wm * 64 + mf * 16 + lq * 4 + r, v * (1.f / 256.f));
            }
    } else if (type == 1) {
        // deconv parities {0,3}: taps {0,2,6,8} then {4}; A3p tap-chunks {0,1,2,3,8}; 20 steps
        const int TIX[5] = {0, 1, 2, 3, 8};
        const int POD[5] = {0, 1, 18, 19, 19};
        stageA(0, 0);
        stageB(0, 0, 0);
#pragma unroll
        for (int ti = 0; ti < 5; ++ti) {
            const int po = POD[ti];
            const int poN = (ti < 4) ? POD[ti + 1] : 0;
#pragma unroll 1
            for (int s = 0; s < 4; ++s) {
                bool last = (ti == 4) && (s == 3);
                int tin = (s < 3) ? ti : ti + 1;
                int sn = (s < 3) ? s + 1 : 0;
                int kAn = last ? 0 : TIX[tin] * 8 + sn * 2;
                kstep(cur, !last, kAn, (s < 3) ? po : poN, sn);
                cur ^= 1;
            }
            if (ti == 3) flush(0, 0);
            else if (ti == 4) flush(1, 1);
        }
        ss = blockSum256(ss, lds4);
        if (t == 0) atomicAdd(pr + ab, ss);
    } else {
        // deconv parities {1,2}: taps {1,7} then {3,5}; A3p tap-chunks {4,5,6,7}; 16 steps
        const int TIX[4] = {4, 5, 6, 7};
        const int POD[4] = {1, 19, 18, 19};
        stageA(0, 32);
        stageB(0, 1, 0);
#pragma unroll
        for (int ti = 0; ti < 4; ++ti) {
            const int po = POD[ti];
            const int poN = (ti < 3) ? POD[ti + 1] : 0;
#pragma unroll 1
            for (int s = 0; s < 4; ++s) {
                bool last = (ti == 3) && (s == 3);
                int tin = (s < 3) ? ti : ti + 1;
                int sn = (s < 3) ? s + 1 : 0;
                int kAn = last ? 0 : TIX[tin & 3] * 8 + sn * 2;
                kstep(cur, !last, kAn, (s < 3) ? po : poN, sn);
                cur ^= 1;
            }
            if (ti == 1) flush(0, 1);
            else if (ti == 3) flush(1, 0);
        }
        ss = blockSum256(ss, lds4);
        if (t == 0) atomicAdd(pr + ab, ss);
    }
}

// ---- metric (mix fused: sets 2/3 from meanbuf; Sinkhorn dead code) ----
__global__ __launch_bounds__(128) void k_metric(const float* __restrict__ feats,
                                                const float* __restrict__ meanbuf,
                                                const float* __restrict__ PnT,
                                                const float* __restrict__ pn2,
                                                const int* __restrict__ la,
                                                const int* __restrict__ lb,
                                                float* __restrict__ mo) {
    __shared__ float lds2[2];
    __shared__ float xs[128];
    int blk = blockIdx.x;
    int t = threadIdx.x;
    int b = blk & 31;
    float xv;
    if (blk < 64) xv = feats[(size_t)blk * CI + t];
    else if (blk < 96) xv = LAMF * meanbuf[b * 128 + t] + ILAMF * meanbuf[12288 + b * 128 + t];
    else xv = LAMF * meanbuf[4096 + b * 128 + t] + ILAMF * meanbuf[8192 + b * 128 + t];
    float ssq = blockSum128(xv * xv, lds2);
    float sc = SCALEF / fmaxf(sqrtf(ssq), 1e-12f);
    float xn = xv * sc;
    xs[t] = xn;
    float xn2 = blockSum128(xn * xn, lds2);
    bool active = (t < NB);
    float Dk = 1e30f;
    if (active) {
        float dot = 0.f;
#pragma unroll 8
        for (int e = 0; e < CI; ++e) dot = fmaf(xs[e], PnT[e * NB + t], dot);
        Dk = xn2 + pn2[t] - 2.f * dot;
    }
    float z = active ? -Dk : -1e30f;
    float m = blockMax128(z, lds2);
    float e = active ? expf(z - m) : 0.f;
    float se = blockSum128(e, lds2);
    float lse = m + logf(se);
    if (t == 0) mo[blk * 3 + 0] = lse;
    int A = la[b], Bb = lb[b];
    if (t == A) mo[blk * 3 + 1] = Dk;
    if (t == Bb) mo[blk * 3 + 2] = Dk;
}

__global__ __launch_bounds__(128) void k_final(const float* __restrict__ pr,
                                               const float* __restrict__ mo,
                                               float* __restrict__ out) {
    __shared__ float mla[4], mlb[4];
    int t = threadIdx.x;
    const float* m = mo + t * 3;
    float ula = m[0] + m[1];
    float ulb = m[0] + m[2];
#pragma unroll
    for (int off = 16; off > 0; off >>= 1) {
        ula += __shfl_down(ula, off, 32);
        ulb += __shfl_down(ulb, off, 32);
    }
    if ((t & 31) == 0) { mla[t >> 5] = ula * (1.f / 32.f); mlb[t >> 5] = ulb * (1.f / 32.f); }
    __syncthreads();
    if (t == 0) {
        float lxa = pr[0] * (1.f / 4194304.f);
        float lxb = pr[1] * (1.f / 4194304.f);
        float lca = mla[0];
        float lcb = mlb[1];
        float lcma = LAMF * mla[2] + ILAMF * mlb[2];
        float lcmb = LAMF * mlb[3] + ILAMF * mla[3];
        out[0] = lxa + lxb + lca + lcb + lcma + lcmb;
        out[1] = lxa; out[2] = lxb; out[3] = lca; out[4] = lcb; out[5] = lcma; out[6] = lcmb;
    }
}

extern "C" void kernel_launch(void* const* d_in, const int* in_sizes, int n_in,
                              void* d_out, int out_size, void* d_ws, size_t ws_size,
                              hipStream_t stream) {
    const float* xa = (const float*)d_in[0];
    const float* xb = (const float*)d_in[1];
    const int* la = (const int*)d_in[2];
    const int* lb = (const int*)d_in[3];
    const float* P = (const float*)d_in[4];
    const float* We = (const float*)d_in[5];
    const float* Wf = (const float*)d_in[6];
    const float* Wd = (const float*)d_in[7];

    char* w = (char*)d_ws;
    const size_t XPAD_B = XSZ * 2 * sizeof(u16);
    const size_t CPAD_B = CSZ * 2 * sizeof(u16);
    const size_t AW_B = (size_t)294912 * 2;
    u16* xpad = (u16*)w;                 w += XPAD_B;
    u16* cpad = (u16*)w;                 w += CPAD_B;
    u16* A1p = (u16*)w;                  w += AW_B;
    u16* A2p = (u16*)w;                  w += AW_B;
    u16* A3p = (u16*)w;                  w += AW_B;
    float* PnT = (float*)w;              w += 12800 * 4;
    float* pn2 = (float*)w;              w += 128 * 4;
    float* feats = (float*)w;            w += 8192 * 4;    // [2 ab][32][128]
    float* meanbuf = (float*)w;          w += 16384 * 4;   // [2 kind][2 ab][32][128]
    float* pr = (float*)w;               w += 16 * 4;
    float* mo = (float*)w;               w += 384 * 4;
    float* out = (float*)d_out;

    hipMemsetAsync(feats, 0, (8192 + 16384 + 16) * sizeof(float), stream);

    k_prep_w<<<1152, 256, 0, stream>>>(We, Wf, Wd, A1p, A2p, A3p);
    k_prox<<<NB, 128, 0, stream>>>(P, PnT, pn2);
    k_ring<<<dim3(32, 2), 256, 0, stream>>>(xpad, cpad);
    k_xpose<<<dim3(32, 16, 2), 256, 0, stream>>>(xa, xb, xpad, meanbuf);
    k_conv1g<<<dim3(4, 32, 4), 256, 0, stream>>>(xpad, A1p, cpad);
    k_cde5<<<dim3(2, 32, 6), 256, 0, stream>>>(cpad, A2p, A3p, xpad, feats, pr);
    k_metric<<<128, 128, 0, stream>>>(feats, meanbuf, PnT, pn2, la, lb, mo);
    k_final<<<1, 128, 0, stream>>>(pr, mo, out);
}

// Round 12
// 104.276 us; speedup vs baseline: 1.0820x; 1.0504x over previous
//
#include <hip/hip_runtime.h>
#include <hip/hip_bf16.h>

#define DEVI __device__ __forceinline__

constexpr int B_ = 32, CI = 128, CM = 256, H_ = 32, W_ = 32;
constexpr int S_ = 1024, NB = 100;
constexpr float LAMF = 0.7f, ILAMF = 0.3f, SCALEF = 3.0f;
// chunked channel-last activation layouts: [b][ch/8][pos][8ch]
constexpr size_t XSZ = (size_t)32 * 16 * 1156 * 8;   // per-ab xpad elems (34x34 pos)
constexpr size_t XBS = (size_t)16 * 1156 * 8;        // per-b stride
constexpr size_t CSZ = (size_t)32 * 32 * 324 * 8;    // per-ab cpad elems (18x18 pos)
constexpr size_t CBS = (size_t)32 * 324 * 8;

typedef short bf8 __attribute__((ext_vector_type(8)));
typedef float f4 __attribute__((ext_vector_type(4)));
typedef unsigned short u16;
typedef unsigned int u32;

struct alignas(8) us4 { u16 v[4]; };
struct alignas(16) us8 { u16 v[8]; };

// deconv tap order, parity-grouped: par0{0,2,6,8} par3{4} | par1{1,7} par2{3,5}
__device__ __constant__ int TAPD9c[9] = {0, 2, 6, 8, 1, 7, 3, 5, 4};

DEVI u16 f2bf(float f) {
    unsigned u = __builtin_bit_cast(unsigned, f);
    u += 0x7FFFu + ((u >> 16) & 1u);
    return (u16)(u >> 16);
}
DEVI float bf2f(u16 h) {
    unsigned u = ((unsigned)h) << 16;
    return __builtin_bit_cast(float, u);
}

DEVI void gll16(const void* g, void* l) {
    __builtin_amdgcn_global_load_lds(
        (const __attribute__((address_space(1))) u32*)g,
        (__attribute__((address_space(3))) u32*)l, 16, 0, 0);
}

DEVI float waveSum(float v) {
#pragma unroll
    for (int off = 32; off > 0; off >>= 1) v += __shfl_down(v, off, 64);
    return v;
}
DEVI float blockSum256(float v, float* lds4) {
    v = waveSum(v);
    int wid = threadIdx.x >> 6, lane = threadIdx.x & 63;
    __syncthreads();
    if (lane == 0) lds4[wid] = v;
    __syncthreads();
    return lds4[0] + lds4[1] + lds4[2] + lds4[3];
}
DEVI float blockSum128(float v, float* lds2) {
    v = waveSum(v);
    int wid = threadIdx.x >> 6, lane = threadIdx.x & 63;
    __syncthreads();
    if (lane == 0) lds2[wid] = v;
    __syncthreads();
    return lds2[0] + lds2[1];
}
DEVI float blockMax128(float v, float* lds2) {
#pragma unroll
    for (int off = 32; off > 0; off >>= 1) v = fmaxf(v, __shfl_down(v, off, 64));
    int wid = threadIdx.x >> 6, lane = threadIdx.x & 63;
    __syncthreads();
    if (lane == 0) lds2[wid] = v;
    __syncthreads();
    return fmaxf(lds2[0], lds2[1]);
}

// ---- weight prep: staging-linear k-slot-major layouts (unchanged from R8) ----
__global__ __launch_bounds__(256) void k_prep_w(const float* __restrict__ We,
                                                const float* __restrict__ Wf,
                                                const float* __restrict__ Wd,
                                                u16* __restrict__ A1p,
                                                u16* __restrict__ A2p,
                                                u16* __restrict__ A3p) {
    int i = blockIdx.x * 256 + threadIdx.x;  // 294912
    {
        int e = i & 7, s = (i >> 3) & 511, j = i >> 12;  // j 0..71
        int Mt = j / 36, kc = j - Mt * 36;
        int tap = kc >> 2, cq = kc & 3;
        int q = s >> 7, m = s & 127;
        int oc = Mt * 128 + m, ch = cq * 32 + q * 8 + e;
        A1p[i] = f2bf(We[((size_t)oc * CI + ch) * 9 + tap]);
    }
    {
        int e = i & 7, s = (i >> 3) & 511, kc = i >> 12;  // 0..71
        int tapi = kc >> 3, cq = kc & 7;
        int q = s >> 7, m = s & 127;
        int ch = cq * 32 + q * 8 + e;
        A2p[i] = f2bf(Wf[((size_t)m * CM + ch) * 9 + tapi]);
        A3p[i] = f2bf(Wd[((size_t)m * CM + ch) * 9 + TAPD9c[tapi]]);
    }
}

// ---- proxies ----
__global__ __launch_bounds__(128) void k_prox(const float* __restrict__ P,
                                              float* __restrict__ PnT,
                                              float* __restrict__ pn2) {
    __shared__ float lds2[2];
    int k = blockIdx.x, t = threadIdx.x;
    float v = P[k * CI + t];
    float ss = blockSum128(v * v, lds2);
    float sc = SCALEF / fmaxf(sqrtf(ss), 1e-12f);
    float pv = v * sc;
    PnT[t * NB + k] = pv;
    float s2 = blockSum128(pv * pv, lds2);
    if (t == 0) pn2[k] = s2;
}

// ---- zero the padding rings of xpad and cpad ----
__global__ __launch_bounds__(256) void k_ring(u16* __restrict__ xpad, u16* __restrict__ cpad) {
    int b = blockIdx.x, ab = blockIdx.y, t = threadIdx.x;
    u16* xp = xpad + (size_t)ab * XSZ + (size_t)b * XBS;
    u16* cp = cpad + (size_t)ab * CSZ + (size_t)b * CBS;
    us8 z = {};
    for (int i = t; i < 132 * 16; i += 256) {
        int cc = i / 132, rp = i - cc * 132;
        int pos;
        if (rp < 68) pos = (rp < 34) ? (32 * 34 + rp) : (33 * 34 + rp - 34);
        else { int r2 = rp - 68; pos = (r2 >> 1) * 34 + 32 + (r2 & 1); }
        *(us8*)(xp + ((size_t)cc * 1156 + pos) * 8) = z;
    }
    for (int i = t; i < 68 * 32; i += 256) {
        int cc = i / 68, rp = i - cc * 68;
        int pos;
        if (rp < 36) pos = (rp < 18) ? rp : (17 * 18 + rp - 18);
        else { int r2 = rp - 36; pos = (1 + (r2 >> 1)) * 18 + ((r2 & 1) ? 17 : 0); }
        *(us8*)(cp + ((size_t)cc * 324 + pos) * 8) = z;
    }
}

// ---- fused: x -> bf16 chunked xpad + invd (LDS-only) + meanx/meanfl ----
__global__ __launch_bounds__(256) void k_xpose(const float* __restrict__ xa,
                                               const float* __restrict__ xb,
                                               u16* __restrict__ xpad,
                                               float* __restrict__ meanbuf) {
    __shared__ float ldsx[128][64];   // 32KB
    __shared__ float sred[256];
    __shared__ float sinv[64];
    int b = blockIdx.x, yg = blockIdx.y, ab = blockIdx.z;
    int t = threadIdx.x;
    const float* x = (ab ? xb : xa) + (size_t)b * CI * S_ + yg * 64;
    int c4 = t >> 6, p = t & 63;
    for (int c0 = 0; c0 < 32; ++c0) {
        int c = c0 * 4 + c4;
        ldsx[c][p] = x[(size_t)c * S_ + p];
    }
    __syncthreads();
    int qc = t >> 6;
    int y = yg * 2 + (p >> 5), xcol = p & 31;
    u16* ox = xpad + (size_t)ab * XSZ + (size_t)b * XBS;
    float ss = 0.f;
#pragma unroll
    for (int c8 = 0; c8 < 4; ++c8) {
        int cb = qc * 32 + c8 * 8;
        int cc = cb >> 3;
        us8 pk;
#pragma unroll
        for (int j = 0; j < 8; ++j) {
            float v = ldsx[cb + j][p];
            ss = fmaf(v, v, ss);
            pk.v[j] = f2bf(v);
        }
        *(us8*)(ox + ((size_t)cc * 1156 + y * 34 + xcol) * 8) = pk;
    }
    sred[t] = ss;
    __syncthreads();
    if (t < 64) {
        float s = sred[t] + sred[t + 64] + sred[t + 128] + sred[t + 192];
        sinv[t] = 1.f / fmaxf(sqrtf(s), 1e-12f);
    }
    __syncthreads();
    int c = t >> 1, h = t & 1;
    float sx = 0.f, sf = 0.f;
    for (int i = 0; i < 32; ++i) {
        int p2 = h * 32 + ((i + c) & 31);
        float v = ldsx[c][p2];
        sx += v;
        sf = fmaf(v, sinv[p2], sf);
    }
    sx += __shfl_xor(sx, 1, 64);
    sf += __shfl_xor(sf, 1, 64);
    if (!(t & 1)) {
        atomicAdd(&meanbuf[(size_t)ab * 4096 + b * 128 + c], sx * (1.f / 1024.f));
        atomicAdd(&meanbuf[8192 + (size_t)ab * 4096 + b * 128 + c], sf * (1.f / 1024.f));
    }
}

// ---- conv1: K-64 steps (18), tile M128 x N64, LDS dbuf (unchanged from R8) ----
__global__ __launch_bounds__(256, 2) void k_conv1g(const u16* __restrict__ XC,
                                                   const u16* __restrict__ A1p,
                                                   u16* __restrict__ CC) {
    __shared__ u16 sA[2][8192];
    __shared__ u16 sB[2][4096];
    int t = threadIdx.x, l = t & 63, l15 = l & 15, lq = l >> 4, w = t >> 6;
    int wm = w & 1, wn = w >> 1;
    int Nt = blockIdx.x, b = blockIdx.y;
    int ab = blockIdx.z & 1, Mt = blockIdx.z >> 1;
    const u16* xc = XC + (size_t)ab * XSZ + (size_t)b * XBS;
    const u16* Ag = A1p + (size_t)Mt * (36 * 4096);
    int bpos0 = (8 * Nt + 2 * (l >> 4)) * 34 + 2 * (l & 15);
    const int po1[9] = {0, 1, 2, 34, 35, 36, 68, 69, 70};

    auto stageA = [&](int buf, int kcA) {
        const u16* ga = Ag + (size_t)kcA * 4096 + t * 8;
        u16* da = &sA[buf][w * 512];
#pragma unroll
        for (int i = 0; i < 4; ++i) gll16(ga + i * 2048, da + i * 2048);
    };
    auto stageB = [&](int buf, int po, int s) {
#pragma unroll
        for (int i = 0; i < 2; ++i) {
            int ks = i * 4 + w;
            gll16(xc + ((size_t)(s * 8 + ks) * 1156 + bpos0 + po) * 8,
                  &sB[buf][(size_t)ks * 512]);
        }
    };

    f4 acc[4][2] = {};
    stageA(0, 0);
    stageB(0, 0, 0);
    int cur = 0;
#pragma unroll
    for (int ti = 0; ti < 9; ++ti) {
        const int po = po1[ti];
        const int poN = (ti < 8) ? po1[ti + 1] : 0;
#pragma unroll 1
        for (int s = 0; s < 2; ++s) {
            __syncthreads();
            bool last = (ti == 8) && (s == 1);
            if (!last) {
                int tin = (s < 1) ? ti : ti + 1;
                int sn = (s < 1) ? 1 : 0;
                stageA(cur ^ 1, tin * 4 + sn * 2);
                stageB(cur ^ 1, (s < 1) ? po : poN, sn);
            }
            const u16* As = sA[cur];
            const u16* Bs = sB[cur];
#pragma unroll
            for (int kc2 = 0; kc2 < 2; ++kc2) {
                bf8 af[4], bv[2];
#pragma unroll
                for (int mf = 0; mf < 4; ++mf)
                    af[mf] = *(const bf8*)(As + ((kc2 * 4 + lq) * 128 + wm * 64 + mf * 16 + l15) * 8);
#pragma unroll
                for (int nf = 0; nf < 2; ++nf)
                    bv[nf] = *(const bf8*)(Bs + ((kc2 * 4 + lq) * 64 + wn * 32 + nf * 16 + l15) * 8);
#pragma unroll
                for (int mf = 0; mf < 4; ++mf)
#pragma unroll
                    for (int nf = 0; nf < 2; ++nf)
                        acc[mf][nf] = __builtin_amdgcn_mfma_f32_16x16x32_bf16(af[mf], bv[nf], acc[mf][nf], 0, 0, 0);
            }
            cur ^= 1;
        }
    }
    u16* cb = CC + (size_t)ab * CSZ + (size_t)b * CBS;
#pragma unroll
    for (int mf = 0; mf < 4; ++mf) {
        int mc = Mt * 128 + wm * 64 + mf * 16 + lq * 4;
#pragma unroll
        for (int nf = 0; nf < 2; ++nf) {
            int nl = wn * 32 + nf * 16 + l15;
            int oh = Nt * 4 + (nl >> 4), ow = nl & 15;
            int posO = (1 + oh) * 18 + 1 + ow;
            us4 pk;
#pragma unroll
            for (int r = 0; r < 4; ++r) pk.v[r] = f2bf(fmaxf(acc[mf][nf][r], 0.f));
            *(us4*)(cb + ((size_t)(mc >> 3) * 324 + posO) * 8 + (mc & 7)) = pk;
        }
    }
}

// ---- k_cde7: resident B-slab + streamed A ----
// tile M128 x N128 (Nt 2); slab = 10 rows x 18 cols x 128ch half = 45KB resident;
// A streams K-64 steps (16KB dbuf). type0 conv2 (36 steps), type1 deconv par{0,3}
// (20), type2 deconv par{1,2} (16). grid (2 Nt, 32 b, 6: type*2+ab)

#define KSTEP(ACC, SUBV, KYV, KXV, HN, KCAN)                                        \
    {                                                                               \
        __syncthreads();                                                            \
        if (HN) stageA(cur ^ 1, (KCAN));                                            \
        const u16* As = sA[cur];                                                    \
        _Pragma("unroll") for (int kc2 = 0; kc2 < 2; ++kc2) {                       \
            bf8 af[4], bv[4];                                                       \
            _Pragma("unroll") for (int mf = 0; mf < 4; ++mf)                        \
                af[mf] = *(const bf8*)(As + kc2 * 4096 + aq + mf * 128);            \
            _Pragma("unroll") for (int nf = 0; nf < 4; ++nf)                        \
                bv[nf] = *(const bf8*)(sS + ((2 * (SUBV) + kc2) * 720 + bq +        \
                                             (nf + (KYV)) * 18 + (KXV)) * 8);      \
            _Pragma("unroll") for (int mf = 0; mf < 4; ++mf)                        \
                _Pragma("unroll") for (int nf = 0; nf < 4; ++nf)                    \
                    ACC[mf][nf] = __builtin_amdgcn_mfma_f32_16x16x32_bf16(          \
                        af[mf], bv[nf], ACC[mf][nf], 0, 0, 0);                      \
        }                                                                           \
        cur ^= 1;                                                                   \
    }

#define FLUSH(ACC, PY, PX)                                                          \
    _Pragma("unroll") for (int mf = 0; mf < 4; ++mf) {                              \
        int mc = wm * 64 + mf * 16 + lq * 4;                                        \
        const u16* xrow = xq + (size_t)(mc >> 3) * 1156 * 8 + (mc & 7);             \
        _Pragma("unroll") for (int nf = 0; nf < 4; ++nf) {                          \
            int n = wn * 64 + nf * 16 + l15;                                        \
            int oh = 8 * Nt + (n >> 4), ow = n & 15;                                \
            int Y = 2 * oh + (PY), X = 2 * ow + (PX);                               \
            us4 xv = *(const us4*)(xrow + (size_t)(Y * 34 + X) * 8);                \
            _Pragma("unroll") for (int r = 0; r < 4; ++r) {                         \
                float d = ACC[mf][nf][r] - bf2f(xv.v[r]);                           \
                ss = fmaf(d, d, ss);                                                \
            }                                                                       \
        }                                                                           \
    }

__global__ __launch_bounds__(256, 2) void k_cde7(const u16* __restrict__ CC,
                                                 const u16* __restrict__ A2p,
                                                 const u16* __restrict__ A3p,
                                                 const u16* __restrict__ XC,
                                                 float* __restrict__ feats,
                                                 float* __restrict__ pr) {
    __shared__ u16 sS[23040];     // [ccL16][pos 10x18][8e] = 45KB resident slab
    __shared__ u16 sA[2][8192];   // A dbuf 2x16KB
    __shared__ float lds4[4];
    int t = threadIdx.x, l = t & 63, l15 = l & 15, lq = l >> 4, w = t >> 6;
    int wm = w & 1, wn = w >> 1;
    int Nt = blockIdx.x, b = blockIdx.y;
    int ab = blockIdx.z & 1, type = blockIdx.z >> 1;
    const u16* cbb = CC + (size_t)ab * CSZ + (size_t)b * CBS;
    const u16* xq = XC + (size_t)ab * XSZ + (size_t)b * XBS;
    const u16* Ag = type ? A3p : A2p;
    int r0 = 8 * Nt;
    int aq = (lq * 128 + wm * 64 + l15) * 8;
    int bq = lq * 180 + wn * 72 + l15;

    auto stageA = [&](int buf, int kcA) {   // 2 chunks = 16KB contiguous
        const u16* ga = Ag + (size_t)kcA * 4096 + t * 8;
        u16* da = &sA[buf][w * 512];
#pragma unroll
        for (int i = 0; i < 4; ++i) gll16(ga + i * 2048, da + i * 2048);
    };
    auto stage_slab = [&](int h) {          // reg-staged copy, 16 chunks x 180 us8
        if (t < 180) {
#pragma unroll 1
            for (int ccL = 0; ccL < 16; ++ccL) {
                int cc = h * 16 + ccL;
                us8 v = *(const us8*)(cbb + ((size_t)cc * 324 + r0 * 18 + t) * 8);
                *(us8*)(sS + ((size_t)ccL * 180 + t) * 8) = v;
            }
        }
    };

    int cur = 0;
    float ss = 0.f;
    if (type == 0) {
        f4 acc[4][4] = {};
        stage_slab(0);
        stageA(0, 0);
#pragma unroll
        for (int h = 0; h < 2; ++h) {
            if (h == 1) { __syncthreads(); stage_slab(1); }
#pragma unroll 1
            for (int st = 0; st < 18; ++st) {
                int s = h * 18 + st;
                int ti = st >> 1, sub = st & 1;
                int ky = ti / 3, kx = ti - ky * 3;
                bool hn = s < 35;
                int s1 = hn ? s + 1 : 0;
                int h1 = s1 / 18, rr = s1 - h1 * 18;
                int kcan = (rr >> 1) * 8 + h1 * 4 + (rr & 1) * 2;
                KSTEP(acc, sub, ky, kx, hn, kcan);
            }
        }
        float* fo = feats + ((size_t)ab * B_ + b) * CI;
#pragma unroll
        for (int mf = 0; mf < 4; ++mf)
#pragma unroll
            for (int r = 0; r < 4; ++r) {
                float v = 0.f;
#pragma unroll
                for (int nf = 0; nf < 4; ++nf) v += fmaxf(acc[mf][nf][r], 0.f);
                v += __shfl_xor(v, 1, 64);
                v += __shfl_xor(v, 2, 64);
                v += __shfl_xor(v, 4, 64);
                v += __shfl_xor(v, 8, 64);
                if (l15 == 0)
                    atomicAdd(fo + wm * 64 + mf * 16 + lq * 4 + r, v * (1.f / 256.f));
            }
    } else if (type == 1) {
        // taps {0,2,6,8} -> accP (par0), tap {4} -> accQ (par3)
        f4 accP[4][4] = {}, accQ[4][4] = {};
        stage_slab(0);
        stageA(0, 0);
#pragma unroll
        for (int h = 0; h < 2; ++h) {
            if (h == 1) { __syncthreads(); stage_slab(1); }
#pragma unroll 1
            for (int st = 0; st < 8; ++st) {
                int s = h * 10 + st;
                int ip = st >> 1, sub = st & 1;
                int dy = ip >> 1, dx = ip & 1;
                bool hn = s < 19;
                int s1 = hn ? s + 1 : 0;
                int h1 = s1 / 10, rr = s1 - h1 * 10;
                int tapi1 = (rr < 8) ? (rr >> 1) : 8;
                int sub1 = (rr < 8) ? (rr & 1) : (rr - 8);
                int kcan = tapi1 * 8 + h1 * 4 + sub1 * 2;
                KSTEP(accP, sub, dy, dx, hn, kcan);
            }
#pragma unroll 1
            for (int st = 0; st < 2; ++st) {
                int s = h * 10 + 8 + st;
                int sub = st;
                bool hn = s < 19;
                int s1 = hn ? s + 1 : 0;
                int h1 = s1 / 10, rr = s1 - h1 * 10;
                int tapi1 = (rr < 8) ? (rr >> 1) : 8;
                int sub1 = (rr < 8) ? (rr & 1) : (rr - 8);
                int kcan = tapi1 * 8 + h1 * 4 + sub1 * 2;
                KSTEP(accQ, sub, 1, 1, hn, kcan);
            }
        }
        FLUSH(accP, 0, 0);
        FLUSH(accQ, 1, 1);
        ss = blockSum256(ss, lds4);
        if (t == 0) atomicAdd(pr + ab, ss);
    } else {
        // tapi {4,5} = taps {1,7} -> accP (par1); tapi {6,7} = taps {3,5} -> accQ (par2)
        f4 accP[4][4] = {}, accQ[4][4] = {};
        stage_slab(0);
        stageA(0, 32);
#pragma unroll
        for (int h = 0; h < 2; ++h) {
            if (h == 1) { __syncthreads(); stage_slab(1); }
#pragma unroll 1
            for (int st = 0; st < 4; ++st) {
                int s = h * 8 + st;
                int ip = st >> 1, sub = st & 1;
                bool hn = s < 15;
                int s1 = hn ? s + 1 : 0;
                int h1 = s1 >> 3, rr = s1 & 7;
                int kcan = (4 + (rr >> 1)) * 8 + h1 * 4 + (rr & 1) * 2;
                KSTEP(accP, sub, ip, 1, hn, kcan);
            }
#pragma unroll 1
            for (int st = 0; st < 4; ++st) {
                int s = h * 8 + 4 + st;
                int iq = st >> 1, sub = st & 1;
                bool hn = s < 15;
                int s1 = hn ? s + 1 : 0;
                int h1 = s1 >> 3, rr = s1 & 7;
                int kcan = (4 + (rr >> 1)) * 8 + h1 * 4 + (rr & 1) * 2;
                KSTEP(accQ, sub, 1, iq, hn, kcan);
            }
        }
        FLUSH(accP, 0, 1);
        FLUSH(accQ, 1, 0);
        ss = blockSum256(ss, lds4);
        if (t == 0) atomicAdd(pr + ab, ss);
    }
}

#undef KSTEP
#undef FLUSH

// ---- metric (mix fused: sets 2/3 from meanbuf; Sinkhorn dead code) ----
__global__ __launch_bounds__(128) void k_metric(const float* __restrict__ feats,
                                                const float* __restrict__ meanbuf,
                                                const float* __restrict__ PnT,
                                                const float* __restrict__ pn2,
                                                const int* __restrict__ la,
                                                const int* __restrict__ lb,
                                                float* __restrict__ mo) {
    __shared__ float lds2[2];
    __shared__ float xs[128];
    int blk = blockIdx.x;
    int t = threadIdx.x;
    int b = blk & 31;
    float xv;
    if (blk < 64) xv = feats[(size_t)blk * CI + t];
    else if (blk < 96) xv = LAMF * meanbuf[b * 128 + t] + ILAMF * meanbuf[12288 + b * 128 + t];
    else xv = LAMF * meanbuf[4096 + b * 128 + t] + ILAMF * meanbuf[8192 + b * 128 + t];
    float ssq = blockSum128(xv * xv, lds2);
    float sc = SCALEF / fmaxf(sqrtf(ssq), 1e-12f);
    float xn = xv * sc;
    xs[t] = xn;
    float xn2 = blockSum128(xn * xn, lds2);
    bool active = (t < NB);
    float Dk = 1e30f;
    if (active) {
        float dot = 0.f;
#pragma unroll 8
        for (int e = 0; e < CI; ++e) dot = fmaf(xs[e], PnT[e * NB + t], dot);
        Dk = xn2 + pn2[t] - 2.f * dot;
    }
    float z = active ? -Dk : -1e30f;
    float m = blockMax128(z, lds2);
    float e = active ? expf(z - m) : 0.f;
    float se = blockSum128(e, lds2);
    float lse = m + logf(se);
    if (t == 0) mo[blk * 3 + 0] = lse;
    int A = la[b], Bb = lb[b];
    if (t == A) mo[blk * 3 + 1] = Dk;
    if (t == Bb) mo[blk * 3 + 2] = Dk;
}

__global__ __launch_bounds__(128) void k_final(const float* __restrict__ pr,
                                               const float* __restrict__ mo,
                                               float* __restrict__ out) {
    __shared__ float mla[4], mlb[4];
    int t = threadIdx.x;
    const float* m = mo + t * 3;
    float ula = m[0] + m[1];
    float ulb = m[0] + m[2];
#pragma unroll
    for (int off = 16; off > 0; off >>= 1) {
        ula += __shfl_down(ula, off, 32);
        ulb += __shfl_down(ulb, off, 32);
    }
    if ((t & 31) == 0) { mla[t >> 5] = ula * (1.f / 32.f); mlb[t >> 5] = ulb * (1.f / 32.f); }
    __syncthreads();
    if (t == 0) {
        float lxa = pr[0] * (1.f / 4194304.f);
        float lxb = pr[1] * (1.f / 4194304.f);
        float lca = mla[0];
        float lcb = mlb[1];
        float lcma = LAMF * mla[2] + ILAMF * mlb[2];
        float lcmb = LAMF * mlb[3] + ILAMF * mla[3];
        out[0] = lxa + lxb + lca + lcb + lcma + lcmb;
        out[1] = lxa; out[2] = lxb; out[3] = lca; out[4] = lcb; out[5] = lcma; out[6] = lcmb;
    }
}

extern "C" void kernel_launch(void* const* d_in, const int* in_sizes, int n_in,
                              void* d_out, int out_size, void* d_ws, size_t ws_size,
                              hipStream_t stream) {
    const float* xa = (const float*)d_in[0];
    const float* xb = (const float*)d_in[1];
    const int* la = (const int*)d_in[2];
    const int* lb = (const int*)d_in[3];
    const float* P = (const float*)d_in[4];
    const float* We = (const float*)d_in[5];
    const float* Wf = (const float*)d_in[6];
    const float* Wd = (const float*)d_in[7];

    char* w = (char*)d_ws;
    const size_t XPAD_B = XSZ * 2 * sizeof(u16);
    const size_t CPAD_B = CSZ * 2 * sizeof(u16);
    const size_t AW_B = (size_t)294912 * 2;
    u16* xpad = (u16*)w;                 w += XPAD_B;
    u16* cpad = (u16*)w;                 w += CPAD_B;
    u16* A1p = (u16*)w;                  w += AW_B;
    u16* A2p = (u16*)w;                  w += AW_B;
    u16* A3p = (u16*)w;                  w += AW_B;
    float* PnT = (float*)w;              w += 12800 * 4;
    float* pn2 = (float*)w;              w += 128 * 4;
    float* feats = (float*)w;            w += 8192 * 4;    // [2 ab][32][128]
    float* meanbuf = (float*)w;          w += 16384 * 4;   // [2 kind][2 ab][32][128]
    float* pr = (float*)w;               w += 16 * 4;
    float* mo = (float*)w;               w += 384 * 4;
    float* out = (float*)d_out;

    hipMemsetAsync(feats, 0, (8192 + 16384 + 16) * sizeof(float), stream);

    k_prep_w<<<1152, 256, 0, stream>>>(We, Wf, Wd, A1p, A2p, A3p);
    k_prox<<<NB, 128, 0, stream>>>(P, PnT, pn2);
    k_ring<<<dim3(32, 2), 256, 0, stream>>>(xpad, cpad);
    k_xpose<<<dim3(32, 16, 2), 256, 0, stream>>>(xa, xb, xpad, meanbuf);
    k_conv1g<<<dim3(4, 32, 4), 256, 0, stream>>>(xpad, A1p, cpad);
    k_cde7<<<dim3(2, 32, 6), 256, 0, stream>>>(cpad, A2p, A3p, xpad, feats, pr);
    k_metric<<<128, 128, 0, stream>>>(feats, meanbuf, PnT, pn2, la, lb, mo);
    k_final<<<1, 128, 0, stream>>>(pr, mo, out);
}